// Round 1
// baseline (222.610 us; speedup 1.0000x reference)
//
#include <hip/hip_runtime.h>
#include <math.h>

#define NT 1024      // tokens = 4*256
#define DM 512       // d_model
#define NN 512       // neurons
#define SCALE 651.8986469044033f   // 4096/(2*pi), rounds to same f32 as reference
#define INVLUT (1.0f/4096.0f)

// ---------------------------------------------------------------------------
// kprep: pack per-(n,d) constants transposed to [d][n] as float4
//        {SCALE/(1+|W|), B*SCALE, attn_cos, attn_sin}
//        and transpose/interleave proj_cos_w/proj_sin_w ([d][n] -> [n][slot][2]x4)
// ---------------------------------------------------------------------------
__global__ __launch_bounds__(256) void kprep(
    const float* __restrict__ W, const float* __restrict__ B,
    const float* __restrict__ AC, const float* __restrict__ AS,
    const float* __restrict__ PC, const float* __restrict__ PS,
    float4* __restrict__ packedT, float* __restrict__ projT)
{
    int idx = blockIdx.x * 256 + threadIdx.x;   // 0..262143
    int row = idx >> 9;                         // coalesced-read row
    int col = idx & 511;

    // packedT: row = n, col = d  (reads coalesced, writes scattered 16B)
    float w = W[idx];
    float b = B[idx];
    float invc = SCALE / (1.0f + fabsf(w));
    packedT[col * NN + row] = make_float4(invc, b * SCALE, AC[idx], AS[idx]);

    // projT: row = d, col = n; layout floats: n*1024 + (d>>2)*8 + (d&3) [+4 for sin]
    float c = PC[idx], s = PS[idx];
    int slot = row >> 2, j = row & 3;
    projT[col * 1024 + slot * 8 + j]     = c;
    projT[col * 1024 + slot * 8 + 4 + j] = s;
}

// ---------------------------------------------------------------------------
// kmain: cos_sum/sin_sum[token][n] reduction over d.
// Block = 256 thr = 4 waves. Grid = 128 token-tiles x 8 neuron-groups.
// Lane owns neuron n = ng*64+lane; wave owns d-range [wv*128, +128); 8 tokens.
// x[t][d] is wave-uniform -> scalar loads. packedT stream: 1 dwordx4/lane/iter.
// ---------------------------------------------------------------------------
__global__ __launch_bounds__(256) void kmain(
    const float* __restrict__ x, const float4* __restrict__ packedT,
    float2* __restrict__ pairs)
{
    const int bid  = blockIdx.x;     // 1024
    const int tile = bid >> 3;       // 0..127
    const int ng   = bid & 7;        // 0..7
    const int tid  = threadIdx.x;
    const int wv   = tid >> 6;       // d-quarter
    const int lane = tid & 63;
    const int d0   = wv * 128;
    const int t0   = tile * 8;

    float accC[8], accS[8];
#pragma unroll
    for (int t = 0; t < 8; ++t) { accC[t] = 0.f; accS[t] = 0.f; }

    const float4* p  = packedT + d0 * NN + (ng * 64 + lane);
    const float*  xb = x + t0 * DM + d0;

    for (int i = 0; i < 128; ++i) {
        float4 pk = p[i * NN];   // {invc, bc, attn_cos, attn_sin} for (n, d0+i)
#pragma unroll
        for (int t = 0; t < 8; ++t) {
            float xv = xb[t * DM + i];                 // wave-uniform (s_load)
            float th = fmaf(xv, pk.x, pk.y);           // theta * SCALE
            float r  = rintf(th);                      // round half-to-even
            float ph = __builtin_amdgcn_fractf(r * INVLUT);  // (idx mod 4096)/4096, exact
            accC[t] = fmaf(__builtin_amdgcn_cosf(ph), pk.z, accC[t]);
            accS[t] = fmaf(__builtin_amdgcn_sinf(ph), pk.w, accS[t]);
        }
    }

    // 4-way cross-wave (d-split) reduction in LDS
    __shared__ float2 red[4][8][64];
#pragma unroll
    for (int t = 0; t < 8; ++t) red[wv][t][lane] = make_float2(accC[t], accS[t]);
    __syncthreads();
#pragma unroll
    for (int k = 0; k < 2; ++k) {
        int pi = tid + k * 256;          // 512 (t,n) pairs, 2 per thread
        int t = pi >> 6, nn2 = pi & 63;
        float2 a = red[0][t][nn2], b = red[1][t][nn2],
               c = red[2][t][nn2], d = red[3][t][nn2];
        pairs[(t0 + t) * NN + ng * 64 + nn2] =
            make_float2(a.x + b.x + c.x + d.x, a.y + b.y + c.y + d.y);
    }
}

// ---------------------------------------------------------------------------
// kproj: out[t][d] = silu( sum_n cs[t][n]*pc[d][n] + ss[t][n]*ps[d][n] )
// Block = 256 thr: 32 float4 d-slots x 8 tokens; grid = 128 tiles x 4 d-groups.
// pairs tile staged in LDS; projT streamed (L1/L2-resident, 2MB total).
// ---------------------------------------------------------------------------
__global__ __launch_bounds__(256) void kproj(
    const float2* __restrict__ pairs, const float4* __restrict__ projT,
    float* __restrict__ out)
{
    const int bid  = blockIdx.x;     // 512
    const int tile = bid >> 2;       // 0..127
    const int dg   = bid & 3;        // 128-d group
    const int tid  = threadIdx.x;
    const int slot = tid & 31;       // float4 d-slot within group
    const int tk   = tid >> 5;       // 0..7 token
    const int t0   = tile * 8;

    __shared__ float2 pl[8][NN];     // 32 KiB: 8 tokens x 512 neurons
    {
        const float4* src = (const float4*)(pairs + t0 * NN);
        float4* dst = (float4*)(&pl[0][0]);
        for (int j2 = tid; j2 < 8 * NN / 2; j2 += 256) dst[j2] = src[j2];
    }
    __syncthreads();

    const int gslot = dg * 32 + slot;            // 0..127
    const float4* pp = projT + gslot * 2;
    float4 acc = make_float4(0.f, 0.f, 0.f, 0.f);
#pragma unroll 4
    for (int nn2 = 0; nn2 < NN; ++nn2) {
        float4 c4 = pp[nn2 * 256];
        float4 s4 = pp[nn2 * 256 + 1];
        float2 cs = pl[tk][nn2];
        acc.x = fmaf(c4.x, cs.x, acc.x);
        acc.y = fmaf(c4.y, cs.x, acc.y);
        acc.z = fmaf(c4.z, cs.x, acc.z);
        acc.w = fmaf(c4.w, cs.x, acc.w);
        acc.x = fmaf(s4.x, cs.y, acc.x);
        acc.y = fmaf(s4.y, cs.y, acc.y);
        acc.z = fmaf(s4.z, cs.y, acc.z);
        acc.w = fmaf(s4.w, cs.y, acc.w);
    }
    float4 o;
    o.x = acc.x / (1.f + expf(-acc.x));
    o.y = acc.y / (1.f + expf(-acc.y));
    o.z = acc.z / (1.f + expf(-acc.z));
    o.w = acc.w / (1.f + expf(-acc.w));
    *(float4*)(out + (t0 + tk) * DM + gslot * 4) = o;
}

// ---------------------------------------------------------------------------
extern "C" void kernel_launch(void* const* d_in, const int* in_sizes, int n_in,
                              void* d_out, int out_size, void* d_ws, size_t ws_size,
                              hipStream_t stream)
{
    const float* x  = (const float*)d_in[0];
    const float* W  = (const float*)d_in[1];
    const float* B  = (const float*)d_in[2];
    const float* AC = (const float*)d_in[3];
    const float* AS = (const float*)d_in[4];
    const float* PC = (const float*)d_in[5];
    const float* PS = (const float*)d_in[6];
    float* out = (float*)d_out;

    char* ws = (char*)d_ws;
    float4* packedT = (float4*)ws;                 // 4 MiB: [d][n] float4
    float4* projT   = (float4*)(ws + (4u << 20));  // 2 MiB: [n][128][2] float4
    float2* pairs   = (float2*)(ws + (6u << 20));  // 4 MiB: [token][n] {cs,ss}

    kprep<<<1024, 256, 0, stream>>>(W, B, AC, AS, PC, PS, packedT, (float*)projT);
    kmain<<<1024, 256, 0, stream>>>(x, packedT, pairs);
    kproj<<<512, 256, 0, stream>>>(pairs, projT, out);
}